// Round 8
// baseline (609.862 us; speedup 1.0000x reference)
//
#include <hip/hip_runtime.h>
#include <hip/hip_cooperative_groups.h>
#include <math.h>
#include <stdint.h>

#define PI2 6.28318530717958647692f

typedef __bf16 bf16x8 __attribute__((ext_vector_type(8)));
typedef float f32x4 __attribute__((ext_vector_type(4)));

typedef __attribute__((address_space(1))) const void gvoid_t;
typedef __attribute__((address_space(3))) void lvoid_t;

__device__ __forceinline__ void g2l16(const void* g, void* l) {
    __builtin_amdgcn_global_load_lds(
        reinterpret_cast<gvoid_t*>(reinterpret_cast<uintptr_t>(g)),
        reinterpret_cast<lvoid_t*>(reinterpret_cast<uintptr_t>(l)),
        16, 0, 0);
}

__device__ __forceinline__ short f2bf(float f) {
    unsigned u = __float_as_uint(f);
    u += 0x7FFFu + ((u >> 16) & 1u);          // round-to-nearest-even
    return (short)(u >> 16);
}

__device__ __forceinline__ unsigned pack2bf(float a, float b) {
    return (unsigned)(unsigned short)f2bf(a) |
           ((unsigned)(unsigned short)f2bf(b) << 16);
}

__device__ __forceinline__ float bflo(unsigned v) { return __uint_as_float(v << 16); }
__device__ __forceinline__ float bfhi(unsigned v) { return __uint_as_float(v & 0xFFFF0000u); }

// ---------------------------------------------------------------------------
// aux unit: one uint4 (8 bf16) of operand prep, indexed by flat element i8.
// ---------------------------------------------------------------------------
__device__ __forceinline__ void aux_unit(
    unsigned i8,
    const float* __restrict__ x,
    const float* __restrict__ Ur, const float* __restrict__ Ui,
    const float* __restrict__ S,
    const float* __restrict__ Vr, const float* __restrict__ Vi,
    short* __restrict__ x_bf, short* __restrict__ B1,
    short* __restrict__ Vcat, short* __restrict__ B2t,
    short* __restrict__ Ucat)
{
    if (i8 < 4194304u) {
        const float4* s4 = (const float4*)(x + i8);
        float4 a = s4[0], b = s4[1];
        uint4 o = {pack2bf(a.x, a.y), pack2bf(a.z, a.w),
                   pack2bf(b.x, b.y), pack2bf(b.z, b.w)};
        *(uint4*)(x_bf + i8) = o;
    } else if (i8 < 12582912u) {
        unsigned i = i8 - 4194304u;
        int c = i >> 12, j0 = i & 4095;
        const float inv_n = 1.0f / 4096.0f;
        float v[8];
        if (c < 1024) {
            if (c == 0) {
                #pragma unroll
                for (int u = 0; u < 8; ++u) v[u] = inv_n;
            } else {
                #pragma unroll
                for (int u = 0; u < 8; ++u) {
                    int t = (c * (j0 + u)) & 4095;
                    v[u] = 2.0f * inv_n * cosf((float)t * (PI2 / 4096.0f));
                }
            }
        } else {
            int m = c - 1024;
            #pragma unroll
            for (int u = 0; u < 8; ++u) {
                int t = (m * (j0 + u)) & 4095;
                v[u] = -2.0f * inv_n * sinf((float)t * (PI2 / 4096.0f));
            }
        }
        uint4 o = {pack2bf(v[0], v[1]), pack2bf(v[2], v[3]),
                   pack2bf(v[4], v[5]), pack2bf(v[6], v[7])};
        *(uint4*)(B1 + i) = o;
    } else if (i8 < 16777216u) {
        unsigned i = i8 - 12582912u;
        int t = i >> 11, c = i & 2047;
        const float* src = (c < 1024) ? (Vr + t * 1024 + c)
                                      : (Vi + t * 1024 + (c - 1024));
        float4 a = ((const float4*)src)[0], b = ((const float4*)src)[1];
        uint4 o = {pack2bf(a.x, a.y), pack2bf(a.z, a.w),
                   pack2bf(b.x, b.y), pack2bf(b.z, b.w)};
        *(uint4*)(Vcat + i) = o;
    } else if (i8 < 18874368u) {
        unsigned i = i8 - 16777216u;
        int k = i >> 10, p0 = i & 1023;
        float sk = S[k];
        const float inv_n = 1.0f / 2048.0f;
        float v[8];
        #pragma unroll
        for (int u = 0; u < 8; ++u) {
            int p = p0 + u;
            float val;
            if (p == 0) val = inv_n;
            else if (p < 512) {
                int t = (p * k) & 2047;
                val = 2.0f * inv_n * cosf((float)t * (PI2 / 2048.0f));
            } else {
                int q = p - 512;
                int t = (q * k) & 2047;
                val = -2.0f * inv_n * sinf((float)t * (PI2 / 2048.0f));
            }
            v[u] = val * sk;
        }
        uint4 o = {pack2bf(v[0], v[1]), pack2bf(v[2], v[3]),
                   pack2bf(v[4], v[5]), pack2bf(v[6], v[7])};
        *(uint4*)(B2t + i) = o;
    } else {
        unsigned i = i8 - 18874368u;
        int o_ = i >> 10, c = i & 1023;
        const float* src = (c < 512) ? (Ur + o_ * 512 + c)
                                     : (Ui + o_ * 512 + (c - 512));
        float4 a = ((const float4*)src)[0], b = ((const float4*)src)[1];
        uint4 o = {pack2bf(a.x, a.y), pack2bf(a.z, a.w),
                   pack2bf(b.x, b.y), pack2bf(b.z, b.w)};
        *(uint4*)(Ucat + i) = o;
    }
}

// ---------------------------------------------------------------------------
// Shared 128x128 MFMA tile core, BK=64, XOR-swizzled LDS (round-4 proven).
// ---------------------------------------------------------------------------
__device__ __forceinline__ void tile_core(
    const short* __restrict__ A, int lda,
    const short* __restrict__ B, int ldb, int K,
    short* As, short* Bs, int bm, int bn, f32x4 (&acc)[4][4])
{
    const int tid  = threadIdx.x;
    const int wave = tid >> 6;
    const int lane = tid & 63;
    const int wm   = (wave >> 1) << 6;
    const int wn   = (wave & 1) << 6;
    const int l16  = lane & 15;
    const int quad = lane >> 4;
    const int rk   = l16 & 7;

    int aoff[4], boff[4], loff[4];
    #pragma unroll
    for (int p = 0; p < 4; ++p) {
        int L   = p * 256 + wave * 64 + lane;
        int row = L >> 3;
        int swz = (L & 7) ^ (row & 7);
        aoff[p] = (bm + row) * lda + swz * 8;
        boff[p] = (bn + row) * ldb + swz * 8;
        loff[p] = L * 8;
    }

    for (int k0 = 0; k0 < K; k0 += 64) {
        __syncthreads();
        #pragma unroll
        for (int p = 0; p < 4; ++p) g2l16(A + aoff[p] + k0, As + loff[p]);
        #pragma unroll
        for (int p = 0; p < 4; ++p) g2l16(B + boff[p] + k0, Bs + loff[p]);
        __syncthreads();

        #pragma unroll
        for (int h = 0; h < 2; ++h) {
            const int cs8 = ((((h << 2) | quad) ^ rk) << 3);
            bf16x8 b[4];
            #pragma unroll
            for (int nt = 0; nt < 4; ++nt)
                b[nt] = *(const bf16x8*)(Bs + (wn + nt * 16 + l16) * 64 + cs8);
            #pragma unroll
            for (int mt = 0; mt < 4; ++mt) {
                bf16x8 a = *(const bf16x8*)(As + (wm + mt * 16 + l16) * 64 + cs8);
                #pragma unroll
                for (int nt = 0; nt < 4; ++nt)
                    acc[mt][nt] = __builtin_amdgcn_mfma_f32_16x16x32_bf16(
                        a, b[nt], acc[mt][nt], 0, 0, 0);
            }
        }
    }
}

__device__ __forceinline__ void store_tile_bf16(
    f32x4 (&acc)[4][4], short* __restrict__ C, int ldc, int bm, int bn)
{
    const int tid  = threadIdx.x;
    const int wave = tid >> 6;
    const int lane = tid & 63;
    const int wm   = (wave >> 1) << 6;
    const int wn   = (wave & 1) << 6;
    const int l16  = lane & 15;
    const int quad = lane >> 4;
    #pragma unroll
    for (int nt = 0; nt < 4; ++nt) {
        int col = bn + wn + nt * 16 + l16;
        #pragma unroll
        for (int mt = 0; mt < 4; ++mt) {
            int rowb = bm + wm + mt * 16 + quad * 4;
            #pragma unroll
            for (int r = 0; r < 4; ++r)
                C[(size_t)(rowb + r) * ldc + col] = f2bf(acc[mt][nt][r]);
        }
    }
}

// Fragment-layout store: 8 coalesced uint4 per thread (round-7 proven).
__device__ __forceinline__ void store_frag(
    f32x4 (&acc)[4][4], short* __restrict__ planeTile)
{
    uint4* p = (uint4*)planeTile;
    const int tid = threadIdx.x;
    #pragma unroll
    for (int c = 0; c < 8; ++c) {
        int nt = c >> 1, mt0 = (c & 1) * 2;
        uint4 o = {pack2bf(acc[mt0][nt][0],     acc[mt0][nt][1]),
                   pack2bf(acc[mt0][nt][2],     acc[mt0][nt][3]),
                   pack2bf(acc[mt0 + 1][nt][0], acc[mt0 + 1][nt][1]),
                   pack2bf(acc[mt0 + 1][nt][2], acc[mt0 + 1][nt][3])};
        p[c * 256 + tid] = o;
    }
}

// Reduce one fragment chunk (tile, c) across SK planes -> row-major output.
template <bool OUT_F32>
__device__ __forceinline__ void reduce_unit(
    const short* __restrict__ P, size_t planeU4, int SK,
    int tile, int c, int tilesX, void* __restrict__ Out, int ldc,
    const float* __restrict__ bias)
{
    const int bm = (tile / tilesX) << 7;
    const int bn = (tile % tilesX) << 7;
    const int tid  = threadIdx.x;
    const int wave = tid >> 6;
    const int lane = tid & 63;
    const int wm   = (wave >> 1) << 6;
    const int wn   = (wave & 1) << 6;
    const int l16  = lane & 15;
    const int quad = lane >> 4;
    const int nt   = c >> 1, mt0 = (c & 1) * 2;

    const uint4* P4 = (const uint4*)P;
    const size_t base = (size_t)tile * 2048 + (size_t)c * 256 + tid;
    float f[8] = {0, 0, 0, 0, 0, 0, 0, 0};
    for (int z = 0; z < SK; ++z) {
        uint4 v = P4[(size_t)z * planeU4 + base];
        f[0] += bflo(v.x); f[1] += bfhi(v.x);
        f[2] += bflo(v.y); f[3] += bfhi(v.y);
        f[4] += bflo(v.z); f[5] += bfhi(v.z);
        f[6] += bflo(v.w); f[7] += bfhi(v.w);
    }
    const int col = bn + wn + nt * 16 + l16;
    float bv = 0.f;
    if (OUT_F32) bv = bias[col];
    #pragma unroll
    for (int j = 0; j < 8; ++j) {
        int mt  = mt0 + (j >> 2);
        int row = bm + wm + mt * 16 + quad * 4 + (j & 3);
        if (OUT_F32)
            ((float*)Out)[(size_t)row * ldc + col] = f[j] + bv;
        else
            ((short*)Out)[(size_t)row * ldc + col] = f2bf(f[j]);
    }
}

// ---------------------------------------------------------------------------
// Cooperative mega-kernel: 7 phases, grid-stride, grid.sync() boundaries.
// ---------------------------------------------------------------------------
__global__ __launch_bounds__(256, 4) void mega(
    const float* __restrict__ x,
    const float* __restrict__ Ur, const float* __restrict__ Ui,
    const float* __restrict__ S,
    const float* __restrict__ Vr, const float* __restrict__ Vi,
    const float* __restrict__ bias,
    short* __restrict__ x_bf, short* __restrict__ B1,
    short* __restrict__ Vcat, short* __restrict__ B2t,
    short* __restrict__ Ucat,
    short* __restrict__ Xp, short* __restrict__ T1,
    short* __restrict__ M2, short* __restrict__ Pp,
    float* __restrict__ out)
{
    __shared__ __align__(16) short As[128 * 64];
    __shared__ __align__(16) short Bs[128 * 64];

    cooperative_groups::grid_group grid = cooperative_groups::this_grid();
    const int nblk = gridDim.x;
    const int blk  = blockIdx.x;
    const int tid  = threadIdx.x;

    // P0: operand prep (11264 units of 256 uint4-threads)
    for (int v = blk; v < 11264; v += nblk)
        aux_unit(((unsigned)v * 256u + tid) * 8u,
                 x, Ur, Ui, S, Vr, Vi, x_bf, B1, Vcat, B2t, Ucat);
    grid.sync();

    // P1: s1 split-K partials (SK=4, Kpart=1024; units 0..511) +
    //     M2 = Ucat @ B2t^T (direct; units 512..1023)
    for (int v = blk; v < 1024; v += nblk) {
        f32x4 acc[4][4];
        #pragma unroll
        for (int i = 0; i < 4; ++i)
            #pragma unroll
            for (int j = 0; j < 4; ++j)
                acc[i][j] = (f32x4){0.f, 0.f, 0.f, 0.f};
        if (v < 512) {
            int z = v >> 7, tile = v & 127;
            int bm = (tile >> 4) << 7, bn = (tile & 15) << 7;
            tile_core(x_bf + z * 1024, 4096, B1 + z * 1024, 4096, 1024,
                      As, Bs, bm, bn, acc);
            store_frag(acc, Pp + (size_t)z * 2097152 + (size_t)tile * 16384);
        } else {
            int u = v - 512;                      // 32 m-tiles x 16 n-tiles
            int bm = (u >> 4) << 7, bn = (u & 15) << 7;
            tile_core(Ucat, 1024, B2t, 1024, 1024, As, Bs, bm, bn, acc);
            store_tile_bf16(acc, M2, 2048, bm, bn);
        }
    }
    grid.sync();

    // P2: reduce s1 partials -> Xp (128 tiles x 8 chunks = 1024 units)
    for (int v = blk; v < 1024; v += nblk)
        reduce_unit<false>(Pp, 262144, 4, v >> 3, v & 7, 16, Xp, 2048, nullptr);
    grid.sync();

    // P3: s2 = Xp @ Vcat^T partials (SK=8, Kpart=256; 1024 units)
    for (int v = blk; v < 1024; v += nblk) {
        f32x4 acc[4][4];
        #pragma unroll
        for (int i = 0; i < 4; ++i)
            #pragma unroll
            for (int j = 0; j < 4; ++j)
                acc[i][j] = (f32x4){0.f, 0.f, 0.f, 0.f};
        int z = v >> 7, tile = v & 127;
        int bm = (tile >> 4) << 7, bn = (tile & 15) << 7;
        tile_core(Xp + z * 256, 2048, Vcat + z * 256, 2048, 256,
                  As, Bs, bm, bn, acc);
        store_frag(acc, Pp + (size_t)z * 2097152 + (size_t)tile * 16384);
    }
    grid.sync();

    // P4: reduce s2 partials -> T1 (SK=8)
    for (int v = blk; v < 1024; v += nblk)
        reduce_unit<false>(Pp, 262144, 8, v >> 3, v & 7, 16, T1, 2048, nullptr);
    grid.sync();

    // P5: s3 = T1 @ M2^T partials (SK=4, Kpart=512; 256 tiles -> 1024 units)
    for (int v = blk; v < 1024; v += nblk) {
        f32x4 acc[4][4];
        #pragma unroll
        for (int i = 0; i < 4; ++i)
            #pragma unroll
            for (int j = 0; j < 4; ++j)
                acc[i][j] = (f32x4){0.f, 0.f, 0.f, 0.f};
        int z = v >> 8, tile = v & 255;
        int bm = (tile >> 5) << 7, bn = (tile & 31) << 7;
        tile_core(T1 + z * 512, 2048, M2 + z * 512, 2048, 512,
                  As, Bs, bm, bn, acc);
        store_frag(acc, Pp + (size_t)z * 4194304 + (size_t)tile * 16384);
    }
    grid.sync();

    // P6: reduce s3 partials + bias -> out (256 tiles x 8 chunks = 2048 units)
    for (int v = blk; v < 2048; v += nblk)
        reduce_unit<true>(Pp, 524288, 4, v >> 3, v & 7, 32, out, 4096, bias);
}

// ---------------------------------------------------------------------------
// Fallback multi-kernel path (round-7 proven), used if cooperative launch
// is unavailable.
// ---------------------------------------------------------------------------
__global__ __launch_bounds__(256) void aux_all8(
    const float* __restrict__ x,
    const float* __restrict__ Ur, const float* __restrict__ Ui,
    const float* __restrict__ S,
    const float* __restrict__ Vr, const float* __restrict__ Vi,
    short* __restrict__ x_bf, short* __restrict__ B1,
    short* __restrict__ Vcat, short* __restrict__ B2t,
    short* __restrict__ Ucat)
{
    aux_unit((blockIdx.x * 256u + threadIdx.x) * 8u,
             x, Ur, Ui, S, Vr, Vi, x_bf, B1, Vcat, B2t, Ucat);
}

__global__ __launch_bounds__(256, 4) void gemm_s1_m2(
    const short* __restrict__ x_bf, const short* __restrict__ B1,
    short* __restrict__ Pp,
    const short* __restrict__ Ucat, const short* __restrict__ B2t,
    short* __restrict__ M2)
{
    __shared__ __align__(16) short As[128 * 64];
    __shared__ __align__(16) short Bs[128 * 64];
    f32x4 acc[4][4];
    #pragma unroll
    for (int i = 0; i < 4; ++i)
        #pragma unroll
        for (int j = 0; j < 4; ++j)
            acc[i][j] = (f32x4){0.f, 0.f, 0.f, 0.f};
    const int z = blockIdx.z;
    if (z < 4) {
        const int bm = blockIdx.y << 7, bn = blockIdx.x << 7;
        const int tile = blockIdx.y * 16 + blockIdx.x;
        tile_core(x_bf + z * 1024, 4096, B1 + z * 1024, 4096, 1024,
                  As, Bs, bm, bn, acc);
        store_frag(acc, Pp + (size_t)z * 2097152 + (size_t)tile * 16384);
    } else {
        const int bm = (blockIdx.y + ((z - 4) << 3)) << 7;
        const int bn = blockIdx.x << 7;
        tile_core(Ucat, 1024, B2t, 1024, 1024, As, Bs, bm, bn, acc);
        store_tile_bf16(acc, M2, 2048, bm, bn);
    }
}

__global__ __launch_bounds__(256, 4) void gemm_sk_frag(
    const short* __restrict__ A, int lda,
    const short* __restrict__ B, int ldb,
    short* __restrict__ P, size_t planeShorts, int Kpart)
{
    __shared__ __align__(16) short As[128 * 64];
    __shared__ __align__(16) short Bs[128 * 64];
    f32x4 acc[4][4];
    #pragma unroll
    for (int i = 0; i < 4; ++i)
        #pragma unroll
        for (int j = 0; j < 4; ++j)
            acc[i][j] = (f32x4){0.f, 0.f, 0.f, 0.f};
    const int bm = blockIdx.y << 7, bn = blockIdx.x << 7;
    const int z = blockIdx.z;
    const int tile = blockIdx.y * gridDim.x + blockIdx.x;
    tile_core(A + (size_t)z * Kpart, lda, B + (size_t)z * Kpart, ldb, Kpart,
              As, Bs, bm, bn, acc);
    store_frag(acc, P + (size_t)z * planeShorts + (size_t)tile * 16384);
}

template <bool OUT_F32>
__global__ __launch_bounds__(256) void reduce_frag(
    const short* __restrict__ P, size_t planeShorts, int SK,
    int tilesX, void* __restrict__ Out, int ldc,
    const float* __restrict__ bias)
{
    reduce_unit<OUT_F32>(P, planeShorts >> 3, SK,
                         (int)(blockIdx.x >> 3), (int)(blockIdx.x & 7),
                         tilesX, Out, ldc, bias);
}

extern "C" void kernel_launch(void* const* d_in, const int* in_sizes, int n_in,
                              void* d_out, int out_size, void* d_ws, size_t ws_size,
                              hipStream_t stream) {
    const float* x    = (const float*)d_in[0];
    const float* Ur   = (const float*)d_in[1];
    const float* Ui   = (const float*)d_in[2];
    const float* S    = (const float*)d_in[3];
    const float* Vr   = (const float*)d_in[4];
    const float* Vi   = (const float*)d_in[5];
    const float* bias = (const float*)d_in[6];
    float* out = (float*)d_out;

    short* ws   = (short*)d_ws;
    short* x_bf = ws;                                  // 1024*4096
    short* B1   = x_bf + (size_t)1024 * 4096;          // 2048*4096
    short* Vcat = B1   + (size_t)2048 * 4096;          // 2048*2048
    short* B2t  = Vcat + (size_t)2048 * 2048;          // 2048*1024
    short* Ucat = B2t  + (size_t)2048 * 1024;          // 4096*1024
    short* Xp   = Ucat + (size_t)4096 * 1024;          // 1024*2048
    short* T1   = Xp   + (size_t)1024 * 2048;          // 1024*2048
    short* M2   = T1   + (size_t)1024 * 2048;          // 4096*2048
    short* Pp   = M2   + (size_t)4096 * 2048;          // partials: 16.78M shorts

    // Try the cooperative mega-kernel first.
    bool coop_ok = false;
    int dev = 0, numCU = 0, occ = 0;
    if (hipGetDevice(&dev) == hipSuccess &&
        hipDeviceGetAttribute(&numCU, hipDeviceAttributeMultiprocessorCount,
                              dev) == hipSuccess &&
        hipOccupancyMaxActiveBlocksPerMultiprocessor(
            &occ, (const void*)mega, 256, 0) == hipSuccess &&
        occ > 0 && numCU > 0) {
        int G = occ * numCU;
        if (G > 1024) G = 1024;
        void* args[] = {
            (void*)&x, (void*)&Ur, (void*)&Ui, (void*)&S, (void*)&Vr,
            (void*)&Vi, (void*)&bias, (void*)&x_bf, (void*)&B1, (void*)&Vcat,
            (void*)&B2t, (void*)&Ucat, (void*)&Xp, (void*)&T1, (void*)&M2,
            (void*)&Pp, (void*)&out};
        hipError_t err = hipLaunchCooperativeKernel(
            (const void*)mega, dim3(G), dim3(256), args, 0, stream);
        if (err == hipSuccess) coop_ok = true;
        else (void)hipGetLastError();
    } else {
        (void)hipGetLastError();
    }

    if (!coop_ok) {
        // Round-7 proven multi-kernel chain.
        aux_all8<<<dim3(11264), 256, 0, stream>>>(
            x, Ur, Ui, S, Vr, Vi, x_bf, B1, Vcat, B2t, Ucat);
        gemm_s1_m2<<<dim3(16, 8, 8), 256, 0, stream>>>(
            x_bf, B1, Pp, Ucat, B2t, M2);
        reduce_frag<false><<<dim3(1024), 256, 0, stream>>>(
            Pp, (size_t)2097152, 4, 16, Xp, 2048, nullptr);
        gemm_sk_frag<<<dim3(16, 8, 8), 256, 0, stream>>>(
            Xp, 2048, Vcat, 2048, Pp, (size_t)2097152, 256);
        reduce_frag<false><<<dim3(1024), 256, 0, stream>>>(
            Pp, (size_t)2097152, 8, 16, T1, 2048, nullptr);
        gemm_sk_frag<<<dim3(32, 8, 4), 256, 0, stream>>>(
            T1, 2048, M2, 2048, Pp, (size_t)4194304, 512);
        reduce_frag<true><<<dim3(2048), 256, 0, stream>>>(
            Pp, (size_t)4194304, 4, 32, out, 4096, bias);
    }
}

// Round 9
// 200.778 us; speedup vs baseline: 3.0375x; 3.0375x over previous
//
#include <hip/hip_runtime.h>
#include <math.h>
#include <stdint.h>

#define PI2 6.28318530717958647692f

typedef __bf16 bf16x8 __attribute__((ext_vector_type(8)));
typedef float f32x4 __attribute__((ext_vector_type(4)));

typedef __attribute__((address_space(1))) const void gvoid_t;
typedef __attribute__((address_space(3))) void lvoid_t;

__device__ __forceinline__ void g2l16(const void* g, void* l) {
    __builtin_amdgcn_global_load_lds(
        reinterpret_cast<gvoid_t*>(reinterpret_cast<uintptr_t>(g)),
        reinterpret_cast<lvoid_t*>(reinterpret_cast<uintptr_t>(l)),
        16, 0, 0);
}

__device__ __forceinline__ short f2bf(float f) {
    unsigned u = __float_as_uint(f);
    u += 0x7FFFu + ((u >> 16) & 1u);          // round-to-nearest-even
    return (short)(u >> 16);
}

__device__ __forceinline__ unsigned pack2bf(float a, float b) {
    return (unsigned)(unsigned short)f2bf(a) |
           ((unsigned)(unsigned short)f2bf(b) << 16);
}

__device__ __forceinline__ float bflo(unsigned v) { return __uint_as_float(v << 16); }
__device__ __forceinline__ float bfhi(unsigned v) { return __uint_as_float(v & 0xFFFF0000u); }

// XCD-locality swizzle: assuming round-robin blk%8 -> XCD placement, give
// each XCD a CONTIGUOUS unit range so its working set fits its private L2.
__device__ __forceinline__ int xcd_swizzle(int blk, int G) {
    return (blk & 7) * (G >> 3) + (blk >> 3);
}

// ---------------------------------------------------------------------------
// Fused aux kernel (round-6 proven), 8 elements per thread, 11264 blocks.
// ---------------------------------------------------------------------------
__global__ __launch_bounds__(256) void aux_all8(
    const float* __restrict__ x,
    const float* __restrict__ Ur, const float* __restrict__ Ui,
    const float* __restrict__ S,
    const float* __restrict__ Vr, const float* __restrict__ Vi,
    short* __restrict__ x_bf, short* __restrict__ B1,
    short* __restrict__ Vcat, short* __restrict__ B2t,
    short* __restrict__ Ucat)
{
    unsigned i8 = (blockIdx.x * 256u + threadIdx.x) * 8u;
    if (i8 < 4194304u) {
        const float4* s4 = (const float4*)(x + i8);
        float4 a = s4[0], b = s4[1];
        uint4 o = {pack2bf(a.x, a.y), pack2bf(a.z, a.w),
                   pack2bf(b.x, b.y), pack2bf(b.z, b.w)};
        *(uint4*)(x_bf + i8) = o;
    } else if (i8 < 12582912u) {
        unsigned i = i8 - 4194304u;
        int c = i >> 12, j0 = i & 4095;
        const float inv_n = 1.0f / 4096.0f;
        float v[8];
        if (c < 1024) {
            if (c == 0) {
                #pragma unroll
                for (int u = 0; u < 8; ++u) v[u] = inv_n;
            } else {
                #pragma unroll
                for (int u = 0; u < 8; ++u) {
                    int t = (c * (j0 + u)) & 4095;
                    v[u] = 2.0f * inv_n * cosf((float)t * (PI2 / 4096.0f));
                }
            }
        } else {
            int m = c - 1024;
            #pragma unroll
            for (int u = 0; u < 8; ++u) {
                int t = (m * (j0 + u)) & 4095;
                v[u] = -2.0f * inv_n * sinf((float)t * (PI2 / 4096.0f));
            }
        }
        uint4 o = {pack2bf(v[0], v[1]), pack2bf(v[2], v[3]),
                   pack2bf(v[4], v[5]), pack2bf(v[6], v[7])};
        *(uint4*)(B1 + i) = o;
    } else if (i8 < 16777216u) {
        unsigned i = i8 - 12582912u;
        int t = i >> 11, c = i & 2047;
        const float* src = (c < 1024) ? (Vr + t * 1024 + c)
                                      : (Vi + t * 1024 + (c - 1024));
        float4 a = ((const float4*)src)[0], b = ((const float4*)src)[1];
        uint4 o = {pack2bf(a.x, a.y), pack2bf(a.z, a.w),
                   pack2bf(b.x, b.y), pack2bf(b.z, b.w)};
        *(uint4*)(Vcat + i) = o;
    } else if (i8 < 18874368u) {
        unsigned i = i8 - 16777216u;
        int k = i >> 10, p0 = i & 1023;
        float sk = S[k];
        const float inv_n = 1.0f / 2048.0f;
        float v[8];
        #pragma unroll
        for (int u = 0; u < 8; ++u) {
            int p = p0 + u;
            float val;
            if (p == 0) val = inv_n;
            else if (p < 512) {
                int t = (p * k) & 2047;
                val = 2.0f * inv_n * cosf((float)t * (PI2 / 2048.0f));
            } else {
                int q = p - 512;
                int t = (q * k) & 2047;
                val = -2.0f * inv_n * sinf((float)t * (PI2 / 2048.0f));
            }
            v[u] = val * sk;
        }
        uint4 o = {pack2bf(v[0], v[1]), pack2bf(v[2], v[3]),
                   pack2bf(v[4], v[5]), pack2bf(v[6], v[7])};
        *(uint4*)(B2t + i) = o;
    } else {
        unsigned i = i8 - 18874368u;
        int o_ = i >> 10, c = i & 1023;
        const float* src = (c < 512) ? (Ur + o_ * 512 + c)
                                     : (Ui + o_ * 512 + (c - 512));
        float4 a = ((const float4*)src)[0], b = ((const float4*)src)[1];
        uint4 o = {pack2bf(a.x, a.y), pack2bf(a.z, a.w),
                   pack2bf(b.x, b.y), pack2bf(b.z, b.w)};
        *(uint4*)(Ucat + i) = o;
    }
}

// ---------------------------------------------------------------------------
// Shared 128x128 MFMA tile core, BK=64, XOR-swizzled LDS (round-4 proven).
// ---------------------------------------------------------------------------
__device__ __forceinline__ void tile_core(
    const short* __restrict__ A, int lda,
    const short* __restrict__ B, int ldb, int K,
    short* As, short* Bs, int bm, int bn, f32x4 (&acc)[4][4])
{
    const int tid  = threadIdx.x;
    const int wave = tid >> 6;
    const int lane = tid & 63;
    const int wm   = (wave >> 1) << 6;
    const int wn   = (wave & 1) << 6;
    const int l16  = lane & 15;
    const int quad = lane >> 4;
    const int rk   = l16 & 7;

    int aoff[4], boff[4], loff[4];
    #pragma unroll
    for (int p = 0; p < 4; ++p) {
        int L   = p * 256 + wave * 64 + lane;
        int row = L >> 3;
        int swz = (L & 7) ^ (row & 7);
        aoff[p] = (bm + row) * lda + swz * 8;
        boff[p] = (bn + row) * ldb + swz * 8;
        loff[p] = L * 8;
    }

    for (int k0 = 0; k0 < K; k0 += 64) {
        __syncthreads();
        #pragma unroll
        for (int p = 0; p < 4; ++p) g2l16(A + aoff[p] + k0, As + loff[p]);
        #pragma unroll
        for (int p = 0; p < 4; ++p) g2l16(B + boff[p] + k0, Bs + loff[p]);
        __syncthreads();

        #pragma unroll
        for (int h = 0; h < 2; ++h) {
            const int cs8 = ((((h << 2) | quad) ^ rk) << 3);
            bf16x8 b[4];
            #pragma unroll
            for (int nt = 0; nt < 4; ++nt)
                b[nt] = *(const bf16x8*)(Bs + (wn + nt * 16 + l16) * 64 + cs8);
            #pragma unroll
            for (int mt = 0; mt < 4; ++mt) {
                bf16x8 a = *(const bf16x8*)(As + (wm + mt * 16 + l16) * 64 + cs8);
                #pragma unroll
                for (int nt = 0; nt < 4; ++nt)
                    acc[mt][nt] = __builtin_amdgcn_mfma_f32_16x16x32_bf16(
                        a, b[nt], acc[mt][nt], 0, 0, 0);
            }
        }
    }
}

__device__ __forceinline__ void store_tile_bf16(
    f32x4 (&acc)[4][4], short* __restrict__ C, int ldc, int bm, int bn)
{
    const int tid  = threadIdx.x;
    const int wave = tid >> 6;
    const int lane = tid & 63;
    const int wm   = (wave >> 1) << 6;
    const int wn   = (wave & 1) << 6;
    const int l16  = lane & 15;
    const int quad = lane >> 4;
    #pragma unroll
    for (int nt = 0; nt < 4; ++nt) {
        int col = bn + wn + nt * 16 + l16;
        #pragma unroll
        for (int mt = 0; mt < 4; ++mt) {
            int rowb = bm + wm + mt * 16 + quad * 4;
            #pragma unroll
            for (int r = 0; r < 4; ++r)
                C[(size_t)(rowb + r) * ldc + col] = f2bf(acc[mt][nt][r]);
        }
    }
}

// Fragment-layout store: 8 coalesced uint4 per thread (round-7 proven).
__device__ __forceinline__ void store_frag(
    f32x4 (&acc)[4][4], short* __restrict__ planeTile)
{
    uint4* p = (uint4*)planeTile;
    const int tid = threadIdx.x;
    #pragma unroll
    for (int c = 0; c < 8; ++c) {
        int nt = c >> 1, mt0 = (c & 1) * 2;
        uint4 o = {pack2bf(acc[mt0][nt][0],     acc[mt0][nt][1]),
                   pack2bf(acc[mt0][nt][2],     acc[mt0][nt][3]),
                   pack2bf(acc[mt0 + 1][nt][0], acc[mt0 + 1][nt][1]),
                   pack2bf(acc[mt0 + 1][nt][2], acc[mt0 + 1][nt][3])};
        p[c * 256 + tid] = o;
    }
}

// Reduce one fragment chunk (tile, c) across SK planes -> row-major output.
template <bool OUT_F32>
__device__ __forceinline__ void reduce_unit(
    const short* __restrict__ P, size_t planeU4, int SK,
    int tile, int c, int tilesX, void* __restrict__ Out, int ldc,
    const float* __restrict__ bias)
{
    const int bm = (tile / tilesX) << 7;
    const int bn = (tile % tilesX) << 7;
    const int tid  = threadIdx.x;
    const int wave = tid >> 6;
    const int lane = tid & 63;
    const int wm   = (wave >> 1) << 6;
    const int wn   = (wave & 1) << 6;
    const int l16  = lane & 15;
    const int quad = lane >> 4;
    const int nt   = c >> 1, mt0 = (c & 1) * 2;

    const uint4* P4 = (const uint4*)P;
    const size_t base = (size_t)tile * 2048 + (size_t)c * 256 + tid;
    float f[8] = {0, 0, 0, 0, 0, 0, 0, 0};
    for (int z = 0; z < SK; ++z) {
        uint4 v = P4[(size_t)z * planeU4 + base];
        f[0] += bflo(v.x); f[1] += bfhi(v.x);
        f[2] += bflo(v.y); f[3] += bfhi(v.y);
        f[4] += bflo(v.z); f[5] += bfhi(v.z);
        f[6] += bflo(v.w); f[7] += bfhi(v.w);
    }
    const int col = bn + wn + nt * 16 + l16;
    float bv = 0.f;
    if (OUT_F32) bv = bias[col];
    #pragma unroll
    for (int j = 0; j < 8; ++j) {
        int mt  = mt0 + (j >> 2);
        int row = bm + wm + mt * 16 + quad * 4 + (j & 3);
        if (OUT_F32)
            ((float*)Out)[(size_t)row * ldc + col] = f[j] + bv;
        else
            ((short*)Out)[(size_t)row * ldc + col] = f2bf(f[j]);
    }
}

// ---------------------------------------------------------------------------
// Merged s1 + M2 dispatch, 1-D grid of 1024 blocks, XCD-swizzled:
//   unit < 512 : stage-1 split-K (SK=4, Kpart=1024), frag-layout partials
//   unit >= 512: M2 = Ucat @ B2t^T (4096x2048, K=1024), row-major direct
// ---------------------------------------------------------------------------
__global__ __launch_bounds__(256, 4) void gemm_s1_m2(
    const short* __restrict__ x_bf, const short* __restrict__ B1,
    short* __restrict__ Pp,
    const short* __restrict__ Ucat, const short* __restrict__ B2t,
    short* __restrict__ M2)
{
    __shared__ __align__(16) short As[128 * 64];
    __shared__ __align__(16) short Bs[128 * 64];

    f32x4 acc[4][4];
    #pragma unroll
    for (int i = 0; i < 4; ++i)
        #pragma unroll
        for (int j = 0; j < 4; ++j)
            acc[i][j] = (f32x4){0.f, 0.f, 0.f, 0.f};

    const int u = xcd_swizzle((int)blockIdx.x, (int)gridDim.x);
    if (u < 512) {
        int z = u >> 7, tile = u & 127;
        int bm = (tile >> 4) << 7, bn = (tile & 15) << 7;
        tile_core(x_bf + z * 1024, 4096, B1 + z * 1024, 4096, 1024,
                  As, Bs, bm, bn, acc);
        store_frag(acc, Pp + (size_t)z * 2097152 + (size_t)tile * 16384);
    } else {
        int m2u = u - 512;                    // 32 m-tiles x 16 n-tiles
        int bm = (m2u >> 4) << 7, bn = (m2u & 15) << 7;
        tile_core(Ucat, 1024, B2t, 1024, 1024, As, Bs, bm, bn, acc);
        store_tile_bf16(acc, M2, 2048, bm, bn);
    }
}

// ---------------------------------------------------------------------------
// Split-K GEMM into fragment-layout bf16 partial planes, 1-D grid,
// XCD-swizzled. tileShift: log2(tiles per plane); tilesXShift: log2(tilesX).
// ---------------------------------------------------------------------------
__global__ __launch_bounds__(256, 4) void gemm_sk_frag(
    const short* __restrict__ A, int lda,
    const short* __restrict__ B, int ldb,
    short* __restrict__ P, size_t planeShorts, int Kpart,
    int tileShift, int tilesXShift)
{
    __shared__ __align__(16) short As[128 * 64];
    __shared__ __align__(16) short Bs[128 * 64];

    f32x4 acc[4][4];
    #pragma unroll
    for (int i = 0; i < 4; ++i)
        #pragma unroll
        for (int j = 0; j < 4; ++j)
            acc[i][j] = (f32x4){0.f, 0.f, 0.f, 0.f};

    const int u    = xcd_swizzle((int)blockIdx.x, (int)gridDim.x);
    const int z    = u >> tileShift;
    const int tile = u & ((1 << tileShift) - 1);
    const int bm   = (tile >> tilesXShift) << 7;
    const int bn   = (tile & ((1 << tilesXShift) - 1)) << 7;

    tile_core(A + (size_t)z * Kpart, lda, B + (size_t)z * Kpart, ldb, Kpart,
              As, Bs, bm, bn, acc);
    store_frag(acc, P + (size_t)z * planeShorts + (size_t)tile * 16384);
}

template <bool OUT_F32>
__global__ __launch_bounds__(256) void reduce_frag(
    const short* __restrict__ P, size_t planeShorts, int SK,
    int tilesX, void* __restrict__ Out, int ldc,
    const float* __restrict__ bias)
{
    reduce_unit<OUT_F32>(P, planeShorts >> 3, SK,
                         (int)(blockIdx.x >> 3), (int)(blockIdx.x & 7),
                         tilesX, Out, ldc, bias);
}

// ---------------------------------------------------------------------------
// Direct GEMM for the small-ws fallback path (round-7 proven)
// ---------------------------------------------------------------------------
template <bool OUT_F32>
__global__ __launch_bounds__(256, 4) void gemm_direct(
    const short* __restrict__ A, int lda,
    const short* __restrict__ B, int ldb,
    void* __restrict__ Cv, int ldc,
    const float* __restrict__ bias, int K)
{
    __shared__ __align__(16) short As[128 * 64];
    __shared__ __align__(16) short Bs[128 * 64];

    f32x4 acc[4][4];
    #pragma unroll
    for (int i = 0; i < 4; ++i)
        #pragma unroll
        for (int j = 0; j < 4; ++j)
            acc[i][j] = (f32x4){0.f, 0.f, 0.f, 0.f};

    const int bm = blockIdx.y << 7;
    const int bn = blockIdx.x << 7;
    tile_core(A, lda, B, ldb, K, As, Bs, bm, bn, acc);

    const int tid  = threadIdx.x;
    const int wave = tid >> 6;
    const int lane = tid & 63;
    const int wm   = (wave >> 1) << 6;
    const int wn   = (wave & 1) << 6;
    const int l16  = lane & 15;
    const int quad = lane >> 4;

    if (OUT_F32) {
        float* C = (float*)Cv;
        #pragma unroll
        for (int nt = 0; nt < 4; ++nt) {
            int col = bn + wn + nt * 16 + l16;
            float bv = bias ? bias[col] : 0.f;
            #pragma unroll
            for (int mt = 0; mt < 4; ++mt) {
                int rowb = bm + wm + mt * 16 + quad * 4;
                #pragma unroll
                for (int r = 0; r < 4; ++r)
                    C[(size_t)(rowb + r) * ldc + col] = acc[mt][nt][r] + bv;
            }
        }
    } else {
        store_tile_bf16(acc, (short*)Cv, ldc, bm, bn);
    }
}

extern "C" void kernel_launch(void* const* d_in, const int* in_sizes, int n_in,
                              void* d_out, int out_size, void* d_ws, size_t ws_size,
                              hipStream_t stream) {
    const float* x    = (const float*)d_in[0];
    const float* Ur   = (const float*)d_in[1];
    const float* Ui   = (const float*)d_in[2];
    const float* S    = (const float*)d_in[3];
    const float* Vr   = (const float*)d_in[4];
    const float* Vi   = (const float*)d_in[5];
    const float* bias = (const float*)d_in[6];
    float* out = (float*)d_out;

    short* ws   = (short*)d_ws;
    short* x_bf = ws;                                  // 1024*4096
    short* B1   = x_bf + (size_t)1024 * 4096;          // 2048*4096
    short* Vcat = B1   + (size_t)2048 * 4096;          // 2048*2048
    short* B2t  = Vcat + (size_t)2048 * 2048;          // 2048*1024
    short* Ucat = B2t  + (size_t)2048 * 1024;          // 4096*1024
    short* Xp   = Ucat + (size_t)4096 * 1024;          // 1024*2048
    short* T1   = Xp   + (size_t)1024 * 2048;          // 1024*2048
    short* M2   = T1   + (size_t)1024 * 2048;          // 4096*2048
    short* Pp   = M2   + (size_t)4096 * 2048;          // partials: 16.78M shorts

    const size_t need = (size_t)((char*)(Pp + (size_t)8 * 1024 * 2048) - (char*)d_ws);

    aux_all8<<<dim3(11264), 256, 0, stream>>>(
        x, Ur, Ui, S, Vr, Vi, x_bf, B1, Vcat, B2t, Ucat);

    if (ws_size >= need) {
        // s1 (SK=4, Kpart=1024, frag partials) + M2 (direct): 1024 blocks
        gemm_s1_m2<<<dim3(1024), 256, 0, stream>>>(
            x_bf, B1, Pp, Ucat, B2t, M2);
        reduce_frag<false><<<dim3(1024), 256, 0, stream>>>(
            Pp, (size_t)2097152, 4, 16, Xp, 2048, nullptr);

        // Stage 2: T1 = X' @ Vcat^T (SK=8, Kpart=256 -> 1024 blocks)
        gemm_sk_frag<<<dim3(1024), 256, 0, stream>>>(
            Xp, 2048, Vcat, 2048, Pp, (size_t)2097152, 256, 7, 4);
        reduce_frag<false><<<dim3(1024), 256, 0, stream>>>(
            Pp, (size_t)2097152, 8, 16, T1, 2048, nullptr);

        // Final: out = T1 @ M2^T + bias (SK=4, Kpart=512 -> 1024 blocks)
        gemm_sk_frag<<<dim3(1024), 256, 0, stream>>>(
            T1, 2048, M2, 2048, Pp, (size_t)4194304, 512, 8, 5);
        reduce_frag<true><<<dim3(2048), 256, 0, stream>>>(
            Pp, (size_t)4194304, 4, 32, out, 4096, bias);
    } else {
        gemm_direct<false><<<dim3(16, 8), 256, 0, stream>>>(
            x_bf, 4096, B1, 4096, Xp, 2048, nullptr, 4096);
        gemm_direct<false><<<dim3(16, 8), 256, 0, stream>>>(
            Xp, 2048, Vcat, 2048, T1, 2048, nullptr, 2048);
        gemm_direct<false><<<dim3(16, 32), 256, 0, stream>>>(
            Ucat, 1024, B2t, 1024, M2, 2048, nullptr, 1024);
        gemm_direct<true><<<dim3(32, 8), 256, 0, stream>>>(
            T1, 2048, M2, 2048, out, 4096, bias, 2048);
    }
}